// Round 11
// baseline (1323.434 us; speedup 1.0000x reference)
//
#include <hip/hip_runtime.h>

#define HH 64
#define WW 64
#define TT 100
#define CO 8                       // all 8 couts per block (halves LDS reads/FMA + x fetch)
#define KS 6
#define LP 2
#define HALO 21                    // 16 + 6 - 1
#define NSITE 441                  // 21*21
#define NG 5                       // 20 timesteps per chunk (5 float4-groups)

__device__ __forceinline__ float stepu(float u, float s, float th, float wx) {
    // u = (u - s*th) + wx  -- exact reference association, no contraction
    return __fadd_rn(__fsub_rn(u, __fmul_rn(s, th)), wx);
}

// Stage x[T0..T0+20) halo into LDS, conv (kh-major sequential FMA, bit-exact
// vs np ref), scan; merge spike bits into per-thread LDS slots (no VGPR bw[]).
template<int T0>
__device__ __forceinline__ void process_chunk(
    const float* __restrict__ xb,
    float4* __restrict__ xs, const float (*wds)[CO],
    unsigned (*bwl)[4][256],
    int tid, int r, int c, int h0, int w0, float th,
    float* ut, float* sprev)
{
    for (int i = tid; i < NSITE * NG; i += 256) {
        const int s  = i / NG;
        const int tg = i - s * NG;
        const int hr = s / HALO;
        const int hc = s - hr * HALO;
        const int hh = h0 - LP + hr;
        const int ww = w0 - LP + hc;
        float4 v = make_float4(0.f, 0.f, 0.f, 0.f);
        if ((unsigned)hh < (unsigned)HH && (unsigned)ww < (unsigned)WW)
            v = *(const float4*)(xb + ((size_t)hh * WW + ww) * TT + T0 + tg * 4);
        xs[tg * NSITE + s] = v;
    }
    __syncthreads();

    unsigned cb[CO];
#pragma unroll
    for (int j = 0; j < CO; ++j) cb[j] = 0u;

    for (int tg = 0; tg < NG; ++tg) {
        float4 wx[CO];
#pragma unroll
        for (int j = 0; j < CO; ++j) wx[j] = make_float4(0.f, 0.f, 0.f, 0.f);
#pragma unroll
        for (int kh = 0; kh < KS; ++kh) {
#pragma unroll
            for (int kw = 0; kw < KS; ++kw) {
                const float4 xv = xs[tg * NSITE + (r + kh) * HALO + (c + kw)];
                const int tap = kh * KS + kw;
#pragma unroll
                for (int j = 0; j < CO; ++j) {
                    const float wd = wds[tap][j];
                    wx[j].x = __fmaf_rn(wd, xv.x, wx[j].x);
                    wx[j].y = __fmaf_rn(wd, xv.y, wx[j].y);
                    wx[j].z = __fmaf_rn(wd, xv.z, wx[j].z);
                    wx[j].w = __fmaf_rn(wd, xv.w, wx[j].w);
                }
            }
        }
        const int sh = tg * 4;
#pragma unroll
        for (int j = 0; j < CO; ++j) {
            float u = ut[j], s = sprev[j];
            unsigned m = 0u;
            u = stepu(u, s, th, wx[j].x); s = (u > 0.f) ? 1.f : 0.f; m |= (u > 0.f) ? 1u : 0u;
            u = stepu(u, s, th, wx[j].y); s = (u > 0.f) ? 1.f : 0.f; m |= (u > 0.f) ? 2u : 0u;
            u = stepu(u, s, th, wx[j].z); s = (u > 0.f) ? 1.f : 0.f; m |= (u > 0.f) ? 4u : 0u;
            u = stepu(u, s, th, wx[j].w); s = (u > 0.f) ? 1.f : 0.f; m |= (u > 0.f) ? 8u : 0u;
            ut[j] = u; sprev[j] = s;
            cb[j] |= m << sh;
        }
    }
    __syncthreads();   // compute done before next chunk overwrites xs

    // merge 20 chunk bits into per-thread LDS words (self-slot only, no hazard)
    constexpr int W0 = T0 / 32;
    constexpr int S  = T0 % 32;
#pragma unroll
    for (int j = 0; j < CO; ++j) {
        bwl[j][W0][tid] |= cb[j] << S;
        if constexpr (S + 20 > 32)
            bwl[j][W0 + 1][tid] |= cb[j] >> ((32 - S) & 31);
    }
}

__global__ __launch_bounds__(256, 2)   // (256,4) starves VGPRs -> spill (R8)
void sconv2d_spike_kernel(const float* __restrict__ x,
                          const float* __restrict__ wgt,
                          const float* __restrict__ thresh,
                          float* __restrict__ out)
{
    __shared__ float4   xs[NG * NSITE];       // 35.28 KB
    __shared__ float    wds[KS * KS][CO];     // 1.15 KB
    __shared__ unsigned bwl[CO][4][256];      // 32 KB spike-bit accumulators
    // total 68.6 KB -> 2 blocks/CU (R7: 2/CU == 4/CU perf)

    const int tid = threadIdx.x;

    // grid = 32 images x 16 tiles
    const int blk = blockIdx.x;
    const int b   = blk >> 4;
    const int tb  = blk & 15;
    const int h0  = (tb >> 2) << 4;
    const int w0  = (tb & 3) << 4;
    const int r   = tid >> 4;
    const int c   = tid & 15;

    for (int i = tid; i < KS * KS * CO; i += 256) {
        const int j   = i / (KS * KS);
        const int tap = i - j * (KS * KS);
        wds[tap][j] = wgt[j * (KS * KS) + tap];
    }
    // zero own bit slots (self-read only -> no barrier needed)
#pragma unroll
    for (int j = 0; j < CO; ++j) {
        bwl[j][0][tid] = 0u; bwl[j][1][tid] = 0u;
        bwl[j][2][tid] = 0u; bwl[j][3][tid] = 0u;
    }
    const float th = thresh[0];

    const float* xb   = x   + (size_t)b * (HH * WW * TT);
    float*       outb = out + (size_t)b * (CO * HH * WW * TT);

    float ut[CO], sprev[CO];
#pragma unroll
    for (int j = 0; j < CO; ++j) { ut[j] = 0.f; sprev[j] = 0.f; }

    process_chunk< 0>(xb, xs, wds, bwl, tid, r, c, h0, w0, th, ut, sprev);
    process_chunk<20>(xb, xs, wds, bwl, tid, r, c, h0, w0, th, ut, sprev);
    process_chunk<40>(xb, xs, wds, bwl, tid, r, c, h0, w0, th, ut, sprev);
    process_chunk<60>(xb, xs, wds, bwl, tid, r, c, h0, w0, th, ut, sprev);
    process_chunk<80>(xb, xs, wds, bwl, tid, r, c, h0, w0, th, ut, sprev);

    __syncthreads();   // bwl complete before cross-thread flush reads

    // ---- flush: bwl is read-only now (no per-co barriers); full-line stores ----
#pragma unroll
    for (int j = 0; j < CO; ++j) {
#pragma unroll
        for (int k = 0; k < 25; ++k) {
            const int idx = tid + k * 256;        // 0..6399
            const int u   = idx / 25;             // site 0..255 (~3 distinct/wave: broadcast)
            const int tt  = (idx - u * 25) * 4;   // t0 of this float4 (4-aligned)
            const unsigned bs = bwl[j][tt >> 5][u] >> (tt & 31);
            float4 v;
            v.x = (float)( bs        & 1u);
            v.y = (float)((bs >> 1)  & 1u);
            v.z = (float)((bs >> 2)  & 1u);
            v.w = (float)((bs >> 3)  & 1u);
            const int rr = u >> 4, cc = u & 15;
            *(float4*)(outb + (((size_t)j * HH + (h0 + rr)) * WW + (w0 + cc)) * TT + tt) = v;
        }
    }
}

extern "C" void kernel_launch(void* const* d_in, const int* in_sizes, int n_in,
                              void* d_out, int out_size, void* d_ws, size_t ws_size,
                              hipStream_t stream) {
    const float* x      = (const float*)d_in[0];
    const float* wgt    = (const float*)d_in[1];
    const float* thresh = (const float*)d_in[2];
    float* out = (float*)d_out;

    dim3 grid(32 * 16);   // images x tiles = 512 (2 per CU)
    dim3 block(256);
    sconv2d_spike_kernel<<<grid, block, 0, stream>>>(x, wgt, thresh, out);
}

// Round 12
// 843.034 us; speedup vs baseline: 1.5698x; 1.5698x over previous
//
#include <hip/hip_runtime.h>

#define HH 64
#define WW 64
#define TT 100
#define CO 8                       // all 8 couts per block (halves LDS reads/FMA + x fetch)
#define KS 6
#define LP 2
#define HALO 21                    // 16 + 6 - 1
#define NSITE 441                  // 21*21
#define NG 5                       // 20 timesteps per chunk (5 float4-groups)

__device__ __forceinline__ float stepu(float u, float s, float th, float wx) {
    // u = (u - s*th) + wx  -- exact reference association, no contraction
    return __fadd_rn(__fsub_rn(u, __fmul_rn(s, th)), wx);
}

// Stage x[T0..T0+20) halo into LDS, conv (kh-major sequential FMA, bit-exact
// vs np ref), scan; merge spike bits into per-thread LDS slots (no VGPR bw[]).
template<int T0>
__device__ __forceinline__ void process_chunk(
    const float* __restrict__ xb,
    float4* __restrict__ xs, const float (*wds)[CO],
    unsigned (*bwl)[4][256],
    int tid, int r, int c, int h0, int w0, float th,
    float* ut, float* sprev)
{
    for (int i = tid; i < NSITE * NG; i += 256) {
        const int s  = i / NG;
        const int tg = i - s * NG;
        const int hr = s / HALO;
        const int hc = s - hr * HALO;
        const int hh = h0 - LP + hr;
        const int ww = w0 - LP + hc;
        float4 v = make_float4(0.f, 0.f, 0.f, 0.f);
        if ((unsigned)hh < (unsigned)HH && (unsigned)ww < (unsigned)WW)
            v = *(const float4*)(xb + ((size_t)hh * WW + ww) * TT + T0 + tg * 4);
        xs[tg * NSITE + s] = v;
    }
    __syncthreads();

    unsigned cb[CO];
#pragma unroll
    for (int j = 0; j < CO; ++j) cb[j] = 0u;

    for (int tg = 0; tg < NG; ++tg) {
        float4 wx[CO];
#pragma unroll
        for (int j = 0; j < CO; ++j) wx[j] = make_float4(0.f, 0.f, 0.f, 0.f);
#pragma unroll
        for (int kh = 0; kh < KS; ++kh) {
#pragma unroll
            for (int kw = 0; kw < KS; ++kw) {
                const float4 xv = xs[tg * NSITE + (r + kh) * HALO + (c + kw)];
                const int tap = kh * KS + kw;
#pragma unroll
                for (int j = 0; j < CO; ++j) {
                    const float wd = wds[tap][j];
                    wx[j].x = __fmaf_rn(wd, xv.x, wx[j].x);
                    wx[j].y = __fmaf_rn(wd, xv.y, wx[j].y);
                    wx[j].z = __fmaf_rn(wd, xv.z, wx[j].z);
                    wx[j].w = __fmaf_rn(wd, xv.w, wx[j].w);
                }
            }
        }
        const int sh = tg * 4;
#pragma unroll
        for (int j = 0; j < CO; ++j) {
            float u = ut[j], s = sprev[j];
            unsigned m = 0u;
            u = stepu(u, s, th, wx[j].x); s = (u > 0.f) ? 1.f : 0.f; m |= (u > 0.f) ? 1u : 0u;
            u = stepu(u, s, th, wx[j].y); s = (u > 0.f) ? 1.f : 0.f; m |= (u > 0.f) ? 2u : 0u;
            u = stepu(u, s, th, wx[j].z); s = (u > 0.f) ? 1.f : 0.f; m |= (u > 0.f) ? 4u : 0u;
            u = stepu(u, s, th, wx[j].w); s = (u > 0.f) ? 1.f : 0.f; m |= (u > 0.f) ? 8u : 0u;
            ut[j] = u; sprev[j] = s;
            cb[j] |= m << sh;
        }
    }
    __syncthreads();   // compute done before next chunk overwrites xs

    // merge 20 chunk bits into per-thread LDS words (self-slot only, no hazard)
    constexpr int W0 = T0 / 32;
    constexpr int S  = T0 % 32;
#pragma unroll
    for (int j = 0; j < CO; ++j) {
        bwl[j][W0][tid] |= cb[j] << S;
        if constexpr (S + 20 > 32)
            bwl[j][W0 + 1][tid] |= cb[j] >> ((32 - S) & 31);
    }
}

// min-waves=1: frees the allocator to ~160-200 VGPRs. (256,2)/(256,4) made the
// heuristic target 128/64 regs and SPILL (R6/R8/R11: 2-5.6 GB scratch traffic).
// LDS 68.6 KB caps us at 2 blocks/CU (8 waves) regardless, and R7 proved
// 2 blocks/CU == 4 blocks/CU perf for this kernel, so nothing is lost.
__global__ __launch_bounds__(256, 1)
void sconv2d_spike_kernel(const float* __restrict__ x,
                          const float* __restrict__ wgt,
                          const float* __restrict__ thresh,
                          float* __restrict__ out)
{
    __shared__ float4   xs[NG * NSITE];       // 35.28 KB
    __shared__ float    wds[KS * KS][CO];     // 1.15 KB
    __shared__ unsigned bwl[CO][4][256];      // 32 KB spike-bit accumulators
    // total 68.6 KB -> 2 blocks/CU

    const int tid = threadIdx.x;

    // grid = 32 images x 16 tiles
    const int blk = blockIdx.x;
    const int b   = blk >> 4;
    const int tb  = blk & 15;
    const int h0  = (tb >> 2) << 4;
    const int w0  = (tb & 3) << 4;
    const int r   = tid >> 4;
    const int c   = tid & 15;

    for (int i = tid; i < KS * KS * CO; i += 256) {
        const int j   = i / (KS * KS);
        const int tap = i - j * (KS * KS);
        wds[tap][j] = wgt[j * (KS * KS) + tap];
    }
    // zero own bit slots (self-read only -> no barrier needed)
#pragma unroll
    for (int j = 0; j < CO; ++j) {
        bwl[j][0][tid] = 0u; bwl[j][1][tid] = 0u;
        bwl[j][2][tid] = 0u; bwl[j][3][tid] = 0u;
    }
    const float th = thresh[0];

    const float* xb   = x   + (size_t)b * (HH * WW * TT);
    float*       outb = out + (size_t)b * (CO * HH * WW * TT);

    float ut[CO], sprev[CO];
#pragma unroll
    for (int j = 0; j < CO; ++j) { ut[j] = 0.f; sprev[j] = 0.f; }

    process_chunk< 0>(xb, xs, wds, bwl, tid, r, c, h0, w0, th, ut, sprev);
    process_chunk<20>(xb, xs, wds, bwl, tid, r, c, h0, w0, th, ut, sprev);
    process_chunk<40>(xb, xs, wds, bwl, tid, r, c, h0, w0, th, ut, sprev);
    process_chunk<60>(xb, xs, wds, bwl, tid, r, c, h0, w0, th, ut, sprev);
    process_chunk<80>(xb, xs, wds, bwl, tid, r, c, h0, w0, th, ut, sprev);

    __syncthreads();   // bwl complete before cross-thread flush reads

    // ---- flush: bwl is read-only now (no per-co barriers); full-line stores ----
#pragma unroll
    for (int j = 0; j < CO; ++j) {
#pragma unroll
        for (int k = 0; k < 25; ++k) {
            const int idx = tid + k * 256;        // 0..6399
            const int u   = idx / 25;             // site 0..255 (~3 distinct/wave: broadcast)
            const int tt  = (idx - u * 25) * 4;   // t0 of this float4 (4-aligned)
            const unsigned bs = bwl[j][tt >> 5][u] >> (tt & 31);
            float4 v;
            v.x = (float)( bs        & 1u);
            v.y = (float)((bs >> 1)  & 1u);
            v.z = (float)((bs >> 2)  & 1u);
            v.w = (float)((bs >> 3)  & 1u);
            const int rr = u >> 4, cc = u & 15;
            *(float4*)(outb + (((size_t)j * HH + (h0 + rr)) * WW + (w0 + cc)) * TT + tt) = v;
        }
    }
}

extern "C" void kernel_launch(void* const* d_in, const int* in_sizes, int n_in,
                              void* d_out, int out_size, void* d_ws, size_t ws_size,
                              hipStream_t stream) {
    const float* x      = (const float*)d_in[0];
    const float* wgt    = (const float*)d_in[1];
    const float* thresh = (const float*)d_in[2];
    float* out = (float*)d_out;

    dim3 grid(32 * 16);   // images x tiles = 512 (2 per CU)
    dim3 block(256);
    sconv2d_spike_kernel<<<grid, block, 0, stream>>>(x, wgt, thresh, out);
}